// Round 7
// baseline (680.889 us; speedup 1.0000x reference)
//
#include <hip/hip_runtime.h>

// B=32, C=64, H=W=128, RADIUS=30
// d_ws layout: [0, 134MB) = x_h, [134MB, 268MB) = e   (em never materialized)
// After k_dws completes, x_h is dead; 4KB of it is memset to 0 and used as
// the zero-source for k_edge_final's OOB staging lanes.

__device__ __forceinline__ float2 cmul(float2 a, float2 b) {
  return make_float2(a.x * b.x - a.y * b.y, a.x * b.y + a.y * b.x);
}
__device__ __forceinline__ float2 cadd(float2 a, float2 b) {
  return make_float2(a.x + b.x, a.y + b.y);
}
__device__ __forceinline__ float2 csub(float2 a, float2 b) {
  return make_float2(a.x - b.x, a.y - b.y);
}
__device__ __forceinline__ float2 conjf2(float2 a) {
  return make_float2(a.x, -a.y);
}

// async global->LDS, 16B per lane; LDS dest is wave-uniform base + lane*16.
// CONTRACT: lane 0 of every issuing wave must be active.
__device__ __forceinline__ void gload16(const float* g, void* l) {
  __builtin_amdgcn_global_load_lds(
      (const __attribute__((address_space(1))) void*)g,
      (__attribute__((address_space(3))) void*)l, 16, 0, 0);
}

// LDS layout for FFT: element (r,c) at (r<<7) | ((c ^ (c>>4)) ^ (r&31)).
// c^(c>>4) folds the high bits of c into the bank index so ROW passes
// (strided el within a line) spread across bank-pairs; column passes
// (consecutive c across lanes) stay conflict-free. Round-6 counter showed
// 24.35M conflict cycles from the row passes with the plain c^(r&31) layout.
__device__ __forceinline__ int swz(int r, int c) {
  return (r << 7) | ((c ^ (c >> 4)) ^ (r & 31));
}

// ---------------------------------------------------------------------------
// Kernel 1: FFT high-pass, radix-8 passes.
// ---------------------------------------------------------------------------
__device__ __forceinline__ void bf3_fwd(float2 x[8], float2 t0, float2 t1,
                                        float2 t2, float2 t3, float2 tp0,
                                        float2 tp1, float2 tpp) {
  float2 y0 = cadd(x[0], x[4]), y4 = cmul(csub(x[0], x[4]), t0);
  float2 y1 = cadd(x[1], x[5]), y5 = cmul(csub(x[1], x[5]), t1);
  float2 y2 = cadd(x[2], x[6]), y6 = cmul(csub(x[2], x[6]), t2);
  float2 y3 = cadd(x[3], x[7]), y7 = cmul(csub(x[3], x[7]), t3);
  float2 z0 = cadd(y0, y2), z2 = cmul(csub(y0, y2), tp0);
  float2 z1 = cadd(y1, y3), z3 = cmul(csub(y1, y3), tp1);
  float2 z4 = cadd(y4, y6), z6 = cmul(csub(y4, y6), tp0);
  float2 z5 = cadd(y5, y7), z7 = cmul(csub(y5, y7), tp1);
  x[0] = cadd(z0, z1); x[1] = cmul(csub(z0, z1), tpp);
  x[2] = cadd(z2, z3); x[3] = cmul(csub(z2, z3), tpp);
  x[4] = cadd(z4, z5); x[5] = cmul(csub(z4, z5), tpp);
  x[6] = cadd(z6, z7); x[7] = cmul(csub(z6, z7), tpp);
}

__device__ __forceinline__ void bf3_inv(float2 x[8], float2 w0, float2 w10,
                                        float2 w11, float2 w20, float2 w21,
                                        float2 w22, float2 w23) {
  float2 t;
  t = cmul(x[1], w0); float2 y0 = cadd(x[0], t), y1 = csub(x[0], t);
  t = cmul(x[3], w0); float2 y2 = cadd(x[2], t), y3 = csub(x[2], t);
  t = cmul(x[5], w0); float2 y4 = cadd(x[4], t), y5 = csub(x[4], t);
  t = cmul(x[7], w0); float2 y6 = cadd(x[6], t), y7 = csub(x[6], t);
  t = cmul(y2, w10); float2 z0 = cadd(y0, t), z2 = csub(y0, t);
  t = cmul(y3, w11); float2 z1 = cadd(y1, t), z3 = csub(y1, t);
  t = cmul(y6, w10); float2 z4 = cadd(y4, t), z6 = csub(y4, t);
  t = cmul(y7, w11); float2 z5 = cadd(y5, t), z7 = csub(y5, t);
  t = cmul(z4, w20); x[0] = cadd(z0, t); x[4] = csub(z0, t);
  t = cmul(z5, w21); x[1] = cadd(z1, t); x[5] = csub(z1, t);
  t = cmul(z6, w22); x[2] = cadd(z2, t); x[6] = csub(z2, t);
  t = cmul(z7, w23); x[3] = cadd(z3, t); x[7] = csub(z3, t);
}

template <bool COL, int S>
__device__ __forceinline__ void fwd_tri(float2* img, const float2* tw,
                                        int tid) {
  constexpr int m4 = 1 << (S - 2);
#pragma unroll
  for (int k = 0; k < 2; ++k) {
    int g = tid + (k << 10);
    int line = COL ? (g & 127) : (g >> 4);
    int gidx = COL ? (g >> 7) : (g & 15);
    int q = gidx >> (S - 2);
    int j = gidx & (m4 - 1);
    int off0 = (q << (S + 1)) + j;
    int ad[8];
    float2 x[8];
#pragma unroll
    for (int i = 0; i < 8; ++i) {
      int el = off0 + i * m4;
      ad[i] = COL ? swz(el, line) : swz(line, el);
      x[i] = img[ad[i]];
    }
    bf3_fwd(x, tw[j << (6 - S)], tw[(j + m4) << (6 - S)],
            tw[(j + 2 * m4) << (6 - S)], tw[(j + 3 * m4) << (6 - S)],
            tw[j << (7 - S)], tw[(j + m4) << (7 - S)], tw[j << (8 - S)]);
#pragma unroll
    for (int i = 0; i < 8; ++i) img[ad[i]] = x[i];
  }
  __syncthreads();
}

__device__ __forceinline__ void fwd_rows6_g(const float* __restrict__ p0,
                                            const float* __restrict__ p1,
                                            float2* img, const float2* tw,
                                            int tid) {
#pragma unroll
  for (int k = 0; k < 2; ++k) {
    int g = tid + (k << 10);
    int line = g >> 4;
    int j = g & 15;
    float2 x[8];
#pragma unroll
    for (int i = 0; i < 8; ++i) {
      int a = (line << 7) + j + (i << 4);
      x[i] = make_float2(p0[a], p1[a]);
    }
    bf3_fwd(x, tw[j], tw[j + 16], tw[j + 32], tw[j + 48], tw[j << 1],
            tw[(j + 16) << 1], tw[j << 2]);
#pragma unroll
    for (int i = 0; i < 8; ++i) img[swz(line, j + (i << 4))] = x[i];
  }
  __syncthreads();
}

__device__ __forceinline__ void fwd_last_rows(float2* img, int tid) {
#pragma unroll
  for (int k = 0; k < 8; ++k) {
    int g = tid + (k << 10);
    int line = g >> 6;
    int pr = g & 63;
    int e0 = pr << 1;
    int a0 = swz(line, e0), a1 = swz(line, e0 + 1);
    float2 a = img[a0], b = img[a1];
    img[a0] = cadd(a, b);
    img[a1] = csub(a, b);
  }
  __syncthreads();
}

__device__ __forceinline__ void fwd_last_cols_mask(float2* img, int tid) {
#pragma unroll
  for (int k = 0; k < 8; ++k) {
    int g = tid + (k << 10);
    int line = g & 127;
    int pr = g >> 7;
    int e0 = pr << 1;
    int a0 = swz(e0, line), a1 = swz(e0 + 1, line);
    float2 a = img[a0], b = img[a1];
    float2 s = cadd(a, b), d = csub(a, b);
    int v = __brev((unsigned)line) >> 25;
    int dv = v - ((v >= 64) << 7);
    int u0 = __brev((unsigned)e0) >> 25;
    int du0 = u0 - ((u0 >= 64) << 7);
    int u1 = __brev((unsigned)(e0 + 1)) >> 25;
    int du1 = u1 - ((u1 >= 64) << 7);
    int dvv = dv * dv;
    img[a0] = (du0 * du0 + dvv < 900) ? make_float2(0.f, 0.f) : s;
    img[a1] = (du1 * du1 + dvv < 900) ? make_float2(0.f, 0.f) : d;
  }
  __syncthreads();
}

template <bool COL, int S>
__device__ __forceinline__ void inv_tri(float2* img, const float2* tw,
                                        int tid) {
  constexpr int m = 1 << S;
#pragma unroll
  for (int k = 0; k < 2; ++k) {
    int g = tid + (k << 10);
    int line = COL ? (g & 127) : (g >> 4);
    int gidx = COL ? (g >> 7) : (g & 15);
    int q = gidx >> S;
    int j = gidx & (m - 1);
    int off0 = (q << (S + 3)) + j;
    int ad[8];
    float2 x[8];
#pragma unroll
    for (int i = 0; i < 8; ++i) {
      int el = off0 + i * m;
      ad[i] = COL ? swz(el, line) : swz(line, el);
      x[i] = img[ad[i]];
    }
    bf3_inv(x, conjf2(tw[j << (6 - S)]), conjf2(tw[j << (5 - S)]),
            conjf2(tw[(j + m) << (5 - S)]), conjf2(tw[j << (4 - S)]),
            conjf2(tw[(j + m) << (4 - S)]), conjf2(tw[(j + 2 * m) << (4 - S)]),
            conjf2(tw[(j + 3 * m) << (4 - S)]));
#pragma unroll
    for (int i = 0; i < 8; ++i) img[ad[i]] = x[i];
  }
  __syncthreads();
}

__device__ __forceinline__ void inv_last_cols(float2* img, const float2* tw,
                                              int tid) {
#pragma unroll
  for (int k = 0; k < 8; ++k) {
    int g = tid + (k << 10);
    int line = g & 127;
    int j = g >> 7;
    int a0 = swz(j, line), a1 = swz(j + 64, line);
    float2 a = img[a0], b = img[a1];
    float2 t = cmul(b, conjf2(tw[j]));
    img[a0] = cadd(a, t);
    img[a1] = csub(a, t);
  }
  __syncthreads();
}

__device__ __forceinline__ void inv_last_rows_store(const float2* img,
                                                    const float2* tw,
                                                    float* __restrict__ q0,
                                                    float* __restrict__ q1,
                                                    int tid) {
#pragma unroll
  for (int k = 0; k < 8; ++k) {
    int g = tid + (k << 10);
    int line = g >> 6;
    int j = g & 63;
    float2 a = img[swz(line, j)], b = img[swz(line, j + 64)];
    float2 t = cmul(b, conjf2(tw[j]));
    float2 o0 = cadd(a, t), o1 = csub(a, t);
    int p = (line << 7) + j;
    q0[p] = fabsf(o0.x) * 6.103515625e-05f;
    q1[p] = fabsf(o0.y) * 6.103515625e-05f;
    q0[p + 64] = fabsf(o1.x) * 6.103515625e-05f;
    q1[p + 64] = fabsf(o1.y) * 6.103515625e-05f;
  }
}

__global__ __launch_bounds__(1024) void k_fft_hp(const float* __restrict__ x,
                                                 float* __restrict__ xh) {
  __shared__ float2 img[16384];
  __shared__ float2 tw[64];
  const int tid = threadIdx.x;
  const size_t base = (size_t)blockIdx.x * 32768;
  const float* p0 = x + base;
  const float* p1 = p0 + 16384;

  if (tid < 64) {
    float ang = -0.04908738521234052f * (float)tid;
    tw[tid] = make_float2(cosf(ang), sinf(ang));
  }
  __syncthreads();

  fwd_rows6_g(p0, p1, img, tw, tid);
  fwd_tri<false, 3>(img, tw, tid);
  fwd_last_rows(img, tid);
  fwd_tri<true, 6>(img, tw, tid);
  fwd_tri<true, 3>(img, tw, tid);
  fwd_last_cols_mask(img, tid);

  inv_tri<true, 0>(img, tw, tid);
  inv_tri<true, 3>(img, tw, tid);
  inv_last_cols(img, tw, tid);
  inv_tri<false, 0>(img, tw, tid);
  inv_tri<false, 3>(img, tw, tid);
  inv_last_rows_store(img, tw, xh + base, xh + base + 16384, tid);
}

// ---------------------------------------------------------------------------
// Kernel 2: fused DWSConv — T4 counted-vmcnt pipeline. 16 chunks of 4 ch;
// each chunk = 512 LDS granules (4 ch x 128, rows 0..99 real + 28 pad), so
// EVERY wave issues exactly 2 global_load_lds per chunk -> per-wave vmcnt is
// uniform. 3 buffers (24KB), depth-2 prefetch, inline-asm s_waitcnt
// vmcnt(2) + raw s_barrier: loads issued at iter c are awaited at end of
// iter c+1 (two compute phases later); vmcnt never drains to 0 mid-loop.
// __syncthreads' vmcnt(0)-before-barrier was the structural drain (round 6:
// all pipes <45% at occupancy 44%).
// ---------------------------------------------------------------------------
#define DWS_G(chunk, buf)                                                      \
  {                                                                            \
    _Pragma("unroll") for (int k2 = 0; k2 < 2; ++k2) {                         \
      int idx = t + (k2 << 8);                                                 \
      gload16(xh + xbase + (size_t)(chunk) * 65536 + offs[k2],                 \
              &inT[buf][idx << 2]);                                            \
    }                                                                          \
  }

#define DWS_FIX(buf)                                                           \
  {                                                                            \
    _Pragma("unroll") for (int k2 = 0; k2 < 2; ++k2) {                         \
      if ((fixm >> k2) & 1)                                                    \
        *(float4*)&inT[buf][(t + (k2 << 8)) << 2] =                            \
            make_float4(0.f, 0.f, 0.f, 0.f);                                   \
    }                                                                          \
  }

__global__ __launch_bounds__(256) void k_dws(
    const float* __restrict__ xh, float* __restrict__ e,
    const float* __restrict__ dw_w, const float* __restrict__ s1,
    const float* __restrict__ b1, const float* __restrict__ pw_w,
    const float* __restrict__ s2, const float* __restrict__ b2) {
  __shared__ __align__(16) float inT[3][2048];  // 3 x (4ch x 128 granules)

  const int t = threadIdx.x;
  const int bb = blockIdx.x >> 6;
  const int ty = (blockIdx.x >> 2) & 15;
  const int tx = blockIdx.x & 3;
  const int r = t >> 5;
  const int x = t & 31;

  const int gy0 = (ty << 3) - 1;   // first halo row
  const int gxb = (tx << 5) - 4;   // float col of granule 0
  const size_t xbase = (size_t)bb << 20;
  const bool bfix = (ty == 0) | (ty == 15) | (tx == 0) | (tx == 3);

  // per-thread staging offsets + OOB fix mask (chunk-invariant).
  // granule idx = t + 256*k2 in [0,512): c = idx>>7, within = idx&127.
  // within<100: real cell (row=within/10, g=within%10); else pad (reads a
  // small in-bounds region, never consumed by compute).
  unsigned fixm = 0;
  int offs[2];
#pragma unroll
  for (int k2 = 0; k2 < 2; ++k2) {
    int idx = t + (k2 << 8);
    int c = idx >> 7;
    int within = idx & 127;
    if (within < 100) {
      int row = within / 10;
      int g = within - row * 10;
      int grow = gy0 + row;
      int gcol = gxb + (g << 2);
      if ((grow < 0) | (grow > 127) | (gcol < 0) | (gcol > 124))
        fixm |= (1u << k2);
      int grc = grow < 0 ? 0 : (grow > 127 ? 127 : grow);
      int gcc = gcol < 0 ? 0 : (gcol > 124 ? 124 : gcol);
      offs[k2] = (c << 14) + (grc << 7) + gcc;
    } else {
      offs[k2] = (within - 100) << 2;  // pad lane: small in-bounds region
    }
  }

  float acc[64];
#pragma unroll
  for (int o = 0; o < 64; ++o) acc[o] = 0.f;

  // prologue: fill pipeline 2 deep
  DWS_G(0, 0);
  DWS_G(1, 1);
  asm volatile("s_waitcnt vmcnt(2)" ::: "memory");  // G(0) landed
  if (bfix) DWS_FIX(0);
  asm volatile("s_waitcnt lgkmcnt(0)" ::: "memory");
  __builtin_amdgcn_s_barrier();
  __builtin_amdgcn_sched_barrier(0);

#pragma unroll 1
  for (int chunk = 0; chunk < 16; ++chunk) {
    if (chunk + 2 < 16) DWS_G(chunk + 2, (chunk + 2) % 3);
    const float* base = &inT[chunk % 3][0];

    float dwv[4];
#pragma unroll
    for (int c = 0; c < 4; ++c) {
      const int cg = (chunk << 2) + c;
      const float* wp = dw_w + cg * 9;              // uniform -> s_load
      const float* p = base + c * 512 + r * 40 + x + 3;  // center col = x+4
      float s = wp[0] * p[0];
      s = fmaf(wp[1], p[1], s);
      s = fmaf(wp[2], p[2], s);
      s = fmaf(wp[3], p[40], s);
      s = fmaf(wp[4], p[41], s);
      s = fmaf(wp[5], p[42], s);
      s = fmaf(wp[6], p[80], s);
      s = fmaf(wp[7], p[81], s);
      s = fmaf(wp[8], p[82], s);
      dwv[c] = fmaxf(fmaf(s, s1[cg], b1[cg]), 0.f);
    }

#pragma unroll
    for (int o = 0; o < 64; ++o) {
      const float* w = pw_w + (o << 6) + (chunk << 2);
#pragma unroll
      for (int c = 0; c < 4; ++c) acc[o] = fmaf(w[c], dwv[c], acc[o]);
    }

    // end-of-iter: ensure G(chunk+1) landed (allow G(chunk+2) in flight)
    if (chunk < 14) {
      asm volatile("s_waitcnt vmcnt(2)" ::: "memory");
    } else {
      asm volatile("s_waitcnt vmcnt(0)" ::: "memory");
    }
    if (bfix && chunk + 1 < 16) DWS_FIX((chunk + 1) % 3);
    asm volatile("s_waitcnt lgkmcnt(0)" ::: "memory");
    __builtin_amdgcn_s_barrier();
    __builtin_amdgcn_sched_barrier(0);
  }

  const int gy = (ty << 3) + r;
  const int gx = (tx << 5) + x;
#pragma unroll
  for (int o = 0; o < 64; ++o) {
    float ev = fmaxf(fmaf(acc[o], s2[o], b2[o]), 0.f);
    e[(((size_t)bb * 64 + o) << 14) + (gy << 7) + gx] = ev;
  }
}

// ---------------------------------------------------------------------------
// Kernel 3: branches + edge + final (unchanged from round 6).
// ---------------------------------------------------------------------------
struct BrParams {
  const float *dw1w, *dw1s, *dw1b, *pw1w, *pw1s, *pw1b;
  const float *dw2w, *dw2s, *dw2b, *pw2w, *pw2s, *pw2b;
  const float *dw3w, *dw3s, *dw3b, *pw3w, *pw3s, *pw3b;
  const float *dw4w, *dw4s, *dw4b, *pw4w, *pw4s, *pw4b;
};

#define EDGE_G(chunk, buf)                                                     \
  {                                                                            \
    _Pragma("unroll") for (int k2 = 0; k2 < 9; ++k2) {                         \
      int idx = t + (k2 << 8);                                                 \
      if (idx < 2080) {                                                        \
        const float* src = eg + ebase + (size_t)(chunk) * 32768 + eoffs[k2];   \
        if ((fixm >> k2) & 1) src = zp;  /* per-lane cndmask */                \
        gload16(src, &sE[buf][idx << 2]);                                      \
      }                                                                        \
    }                                                                          \
  }

__global__ __launch_bounds__(256) void k_edge_final(
    const float* __restrict__ eg, const float* __restrict__ xg,
    float* __restrict__ out, BrParams P, const float* __restrict__ cw,
    const float* __restrict__ cs, const float* __restrict__ cb,
    const float* __restrict__ zp) {
  __shared__ __align__(16) float sE[2][8320];  // 2 x (2ch x 26r x 160f)
  __shared__ float w2r[768], w3r[768], w4r[768];  // [c][12] repacked
  __shared__ float chp[1024];          // [c][16] packed params
  __shared__ float dwSs[4][64], dwBs[4][64], gs[4][64];
  __shared__ float dw1Ws[64], cws[64];
  __shared__ float pss[4][16], pbs[4][16];
  __shared__ float KbS, swS;

  const int t = threadIdx.x;
  const int bb = blockIdx.x >> 3;      // batch
  const int ty = blockIdx.x & 7;       // row-tile of 16
  const int r = t >> 4;                // 0..15
  const int x0 = (t & 15) << 3;        // 0..120, step 8
  const int gy = (ty << 4) + r;
  const int gy0 = (ty << 4) - 5;
  const size_t ebase = (size_t)bb << 20;

  for (int i = t; i < 576; i += 256) {
    int row = i / 9, q = i - row * 9;
    w2r[row * 12 + q] = P.dw2w[i];
    w3r[row * 12 + q] = P.dw3w[i];
    w4r[row * 12 + q] = P.dw4w[i];
  }
  if (t < 64) {
    dw1Ws[t] = P.dw1w[t];
    cws[t] = cw[t];
    dwSs[0][t] = P.dw1s[t]; dwBs[0][t] = P.dw1b[t];
    dwSs[1][t] = P.dw2s[t]; dwBs[1][t] = P.dw2b[t];
    dwSs[2][t] = P.dw3s[t]; dwBs[2][t] = P.dw3b[t];
    dwSs[3][t] = P.dw4s[t]; dwBs[3][t] = P.dw4b[t];
  }
  if (t < 16) {
    pss[0][t] = P.pw1s[t]; pbs[0][t] = P.pw1b[t];
    pss[1][t] = P.pw2s[t]; pbs[1][t] = P.pw2b[t];
    pss[2][t] = P.pw3s[t]; pbs[2][t] = P.pw3b[t];
    pss[3][t] = P.pw4s[t]; pbs[3][t] = P.pw4b[t];
  }
  __syncthreads();
  {
    const int q = t >> 6, c = t & 63;
    const float* pwW = (q == 0) ? P.pw1w : (q == 1) ? P.pw2w
                        : (q == 2) ? P.pw3w : P.pw4w;
    float gv = 0.f;
#pragma unroll
    for (int o = 0; o < 16; ++o)
      gv = fmaf(cws[(q << 4) + o] * pss[q][o], pwW[(o << 6) + c], gv);
    gs[q][c] = gv;
  }
  if (t == 0) {
    float kb = 0.f, sw = 0.f;
#pragma unroll
    for (int i = 0; i < 64; ++i) {
      kb = fmaf(cws[i], pbs[i >> 4][i & 15], kb);
      sw += cws[i];
    }
    KbS = kb;
    swS = sw;
  }
  __syncthreads();
  if (t < 64) {
    float* cp = &chp[t << 4];
    cp[0] = dw1Ws[t];  cp[1] = cws[t];
    cp[2] = dwSs[0][t]; cp[3] = dwBs[0][t];
    cp[4] = dwSs[1][t]; cp[5] = dwBs[1][t];
    cp[6] = dwSs[2][t]; cp[7] = dwBs[2][t];
    cp[8] = dwSs[3][t]; cp[9] = dwBs[3][t];
    cp[10] = gs[0][t]; cp[11] = gs[1][t];
    cp[12] = gs[2][t]; cp[13] = gs[3][t];
  }

  unsigned fixm = 0;
  int eoffs[9];
#pragma unroll
  for (int k2 = 0; k2 < 9; ++k2) {
    int idx = t + (k2 << 8);
    eoffs[k2] = 0;
    if (idx < 2080) {
      int jj = idx >= 1040;
      int rem = idx - (jj ? 1040 : 0);
      int row = rem / 40;
      int q = rem - row * 40;
      int s = q ^ (q >> 3);
      int grow = gy0 + row;
      if ((grow < 0) | (grow > 127) | (s < 2) | (s > 33)) fixm |= (1u << k2);
      int grc = grow < 0 ? 0 : (grow > 127 ? 127 : grow);
      int sc = s < 2 ? 2 : (s > 33 ? 33 : s);
      eoffs[k2] = (jj << 14) + (grc << 7) + (sc << 2) - 8;
    }
  }

  const int gbase = (t & 15) << 1;
  int so[6];
#pragma unroll
  for (int k = 0; k < 6; ++k) {
    int g = gbase + k;
    so[k] = (g ^ (g >> 3)) << 2;
  }

  EDGE_G(0, 0);
  __syncthreads();  // drains vmcnt + chp writes

  float eacc[8], es8[8], sxa[8];
#pragma unroll
  for (int k = 0; k < 8; ++k) { eacc[k] = 0.f; es8[k] = 0.f; sxa[k] = 0.f; }

  const float csv = cs[0], cbv = cb[0];

#pragma unroll 1
  for (int c = 0; c < 32; ++c) {
    if (c + 1 < 32) EDGE_G(c + 1, (c + 1) & 1);  // async, in flight
    const float* bp = &sE[c & 1][0];
#pragma unroll 1
    for (int j = 0; j < 2; ++j) {
      const int cg = (c << 1) + j;
      const float* ldc = bp + j * 4160;
      const float* xp = xg + (((size_t)bb * 64 + cg) << 14) + (gy << 7) + x0;
      float xv[8];
      *(float4*)&xv[0] = *(const float4*)xp;
      *(float4*)&xv[4] = *(const float4*)(xp + 4);
      const float4 Q0 = *(const float4*)&chp[cg << 4];
      const float4 Q1 = *(const float4*)&chp[(cg << 4) + 4];
      const float4 Q2 = *(const float4*)&chp[(cg << 4) + 8];
      const float4 Q3 = *(const float4*)&chp[(cg << 4) + 12];

      float cr[24];
      const float* rowc = ldc + (r + 5) * 160;
      *(float4*)&cr[0] = *(const float4*)(rowc + so[0]);
      *(float4*)&cr[4] = *(const float4*)(rowc + so[1]);
      *(float4*)&cr[8] = *(const float4*)(rowc + so[2]);
      *(float4*)&cr[12] = *(const float4*)(rowc + so[3]);
      *(float4*)&cr[16] = *(const float4*)(rowc + so[4]);
      *(float4*)&cr[20] = *(const float4*)(rowc + so[5]);

#pragma unroll
      for (int k = 0; k < 8; ++k) {
        float ec = cr[8 + k];
        es8[k] = fmaf(Q0.y, ec, es8[k]);
        float d0 = fmaxf(fmaf(ec * Q0.x, Q0.z, Q0.w), 0.f);
        eacc[k] = fmaf(Q2.z, d0, eacc[k]);
      }
      float mm[24], pp[24];
      {
        const float4 w2a = *(const float4*)&w2r[cg * 12];
        const float4 w2b = *(const float4*)&w2r[cg * 12 + 4];
        const float4 w2c = *(const float4*)&w2r[cg * 12 + 8];
        const float* rm = ldc + (r + 4) * 160;
        const float* rp = ldc + (r + 6) * 160;
        *(float4*)&mm[0] = *(const float4*)(rm + so[1]);
        *(float4*)&mm[4] = *(const float4*)(rm + so[2]);
        *(float4*)&mm[8] = *(const float4*)(rm + so[3]);
        *(float4*)&mm[12] = *(const float4*)(rm + so[4]);
        *(float4*)&pp[0] = *(const float4*)(rp + so[1]);
        *(float4*)&pp[4] = *(const float4*)(rp + so[2]);
        *(float4*)&pp[8] = *(const float4*)(rp + so[3]);
        *(float4*)&pp[12] = *(const float4*)(rp + so[4]);
#pragma unroll
        for (int k = 0; k < 8; ++k) {
          float s = w2a.x * mm[3 + k];
          s = fmaf(w2a.y, mm[4 + k], s);
          s = fmaf(w2a.z, mm[5 + k], s);
          s = fmaf(w2a.w, cr[7 + k], s);
          s = fmaf(w2b.x, cr[8 + k], s);
          s = fmaf(w2b.y, cr[9 + k], s);
          s = fmaf(w2b.z, pp[3 + k], s);
          s = fmaf(w2b.w, pp[4 + k], s);
          s = fmaf(w2c.x, pp[5 + k], s);
          float d1 = fmaxf(fmaf(s, Q1.x, Q1.y), 0.f);
          eacc[k] = fmaf(Q2.w, d1, eacc[k]);
        }
      }
      {
        const float4 w3a = *(const float4*)&w3r[cg * 12];
        const float4 w3b = *(const float4*)&w3r[cg * 12 + 4];
        const float4 w3c = *(const float4*)&w3r[cg * 12 + 8];
        const float* rm = ldc + (r + 2) * 160;
        const float* rp = ldc + (r + 8) * 160;
        *(float4*)&mm[0] = *(const float4*)(rm + so[1]);
        *(float4*)&mm[4] = *(const float4*)(rm + so[2]);
        *(float4*)&mm[8] = *(const float4*)(rm + so[3]);
        *(float4*)&mm[12] = *(const float4*)(rm + so[4]);
        *(float4*)&pp[0] = *(const float4*)(rp + so[1]);
        *(float4*)&pp[4] = *(const float4*)(rp + so[2]);
        *(float4*)&pp[8] = *(const float4*)(rp + so[3]);
        *(float4*)&pp[12] = *(const float4*)(rp + so[4]);
#pragma unroll
        for (int k = 0; k < 8; ++k) {
          float s = w3a.x * mm[1 + k];
          s = fmaf(w3a.y, mm[4 + k], s);
          s = fmaf(w3a.z, mm[7 + k], s);
          s = fmaf(w3a.w, cr[5 + k], s);
          s = fmaf(w3b.x, cr[8 + k], s);
          s = fmaf(w3b.y, cr[11 + k], s);
          s = fmaf(w3b.z, pp[1 + k], s);
          s = fmaf(w3b.w, pp[4 + k], s);
          s = fmaf(w3c.x, pp[7 + k], s);
          float d2 = fmaxf(fmaf(s, Q1.z, Q1.w), 0.f);
          eacc[k] = fmaf(Q3.x, d2, eacc[k]);
        }
      }
      {
        const float4 w4a = *(const float4*)&w4r[cg * 12];
        const float4 w4b = *(const float4*)&w4r[cg * 12 + 4];
        const float4 w4c = *(const float4*)&w4r[cg * 12 + 8];
        const float* rm = ldc + (r + 0) * 160;
        const float* rp = ldc + (r + 10) * 160;
        *(float4*)&mm[0] = *(const float4*)(rm + so[0]);
        *(float4*)&mm[4] = *(const float4*)(rm + so[1]);
        *(float4*)&mm[8] = *(const float4*)(rm + so[2]);
        *(float4*)&mm[12] = *(const float4*)(rm + so[3]);
        *(float4*)&mm[16] = *(const float4*)(rm + so[4]);
        *(float4*)&mm[20] = *(const float4*)(rm + so[5]);
        *(float4*)&pp[0] = *(const float4*)(rp + so[0]);
        *(float4*)&pp[4] = *(const float4*)(rp + so[1]);
        *(float4*)&pp[8] = *(const float4*)(rp + so[2]);
        *(float4*)&pp[12] = *(const float4*)(rp + so[3]);
        *(float4*)&pp[16] = *(const float4*)(rp + so[4]);
        *(float4*)&pp[20] = *(const float4*)(rp + so[5]);
#pragma unroll
        for (int k = 0; k < 8; ++k) {
          float s = w4a.x * mm[3 + k];
          s = fmaf(w4a.y, mm[8 + k], s);
          s = fmaf(w4a.z, mm[13 + k], s);
          s = fmaf(w4a.w, cr[3 + k], s);
          s = fmaf(w4b.x, cr[8 + k], s);
          s = fmaf(w4b.y, cr[13 + k], s);
          s = fmaf(w4b.z, pp[3 + k], s);
          s = fmaf(w4b.w, pp[8 + k], s);
          s = fmaf(w4c.x, pp[13 + k], s);
          float d3 = fmaxf(fmaf(s, Q2.x, Q2.y), 0.f);
          eacc[k] = fmaf(Q3.y, d3, eacc[k]);
        }
      }
#pragma unroll
      for (int k = 0; k < 8; ++k) sxa[k] = fmaf(Q0.y, xv[k], sxa[k]);
    }
    __syncthreads();  // drains c+1 loads; protects buffer reuse
  }

  const float kb = KbS, sw = swS;
  float ov[8];
#pragma unroll
  for (int k = 0; k < 8; ++k) {
    float ee = fmaxf(fmaf(eacc[k] + kb + es8[k], csv, cbv), 0.f);
    ov[k] = fmaf(sxa[k] + ee * sw, csv, cbv);
  }
  float* op = out + ((size_t)bb << 14) + (gy << 7) + x0;
  *(float4*)op = *(float4*)&ov[0];
  *(float4*)(op + 4) = *(float4*)&ov[4];
}

// ---------------------------------------------------------------------------
extern "C" void kernel_launch(void* const* d_in, const int* in_sizes, int n_in,
                              void* d_out, int out_size, void* d_ws,
                              size_t ws_size, hipStream_t stream) {
  (void)in_sizes; (void)n_in; (void)out_size; (void)ws_size;
  const float* x = (const float*)d_in[0];
  const float* dws_dw = (const float*)d_in[1];
  const float* dws_s1 = (const float*)d_in[2];
  const float* dws_b1 = (const float*)d_in[3];
  const float* dws_pw = (const float*)d_in[4];
  const float* dws_s2 = (const float*)d_in[5];
  const float* dws_b2 = (const float*)d_in[6];
  BrParams P;
  P.dw1w = (const float*)d_in[7];  P.dw1s = (const float*)d_in[8];
  P.dw1b = (const float*)d_in[9];  P.pw1w = (const float*)d_in[10];
  P.pw1s = (const float*)d_in[11]; P.pw1b = (const float*)d_in[12];
  P.dw2w = (const float*)d_in[13]; P.dw2s = (const float*)d_in[14];
  P.dw2b = (const float*)d_in[15]; P.pw2w = (const float*)d_in[16];
  P.pw2s = (const float*)d_in[17]; P.pw2b = (const float*)d_in[18];
  P.dw3w = (const float*)d_in[19]; P.dw3s = (const float*)d_in[20];
  P.dw3b = (const float*)d_in[21]; P.pw3w = (const float*)d_in[22];
  P.pw3s = (const float*)d_in[23]; P.pw3b = (const float*)d_in[24];
  P.dw4w = (const float*)d_in[25]; P.dw4s = (const float*)d_in[26];
  P.dw4b = (const float*)d_in[27]; P.pw4w = (const float*)d_in[28];
  P.pw4s = (const float*)d_in[29]; P.pw4b = (const float*)d_in[30];
  const float* conv_w = (const float*)d_in[31];
  const float* conv_s = (const float*)d_in[32];
  const float* conv_b = (const float*)d_in[33];

  float* xh = (float*)d_ws;                 // 134 MB
  float* e = xh + (size_t)33554432;         // 134 MB

  hipLaunchKernelGGL(k_fft_hp, dim3(1024), dim3(1024), 0, stream, x, xh);
  hipLaunchKernelGGL(k_dws, dim3(2048), dim3(256), 0, stream, xh, e, dws_dw,
                     dws_s1, dws_b1, dws_pw, dws_s2, dws_b2);
  // x_h is dead from here; zero 4KB of it as the OOB source for k_edge_final
  hipMemsetAsync(xh, 0, 4096, stream);
  hipLaunchKernelGGL(k_edge_final, dim3(256), dim3(256), 0, stream, e, x,
                     (float*)d_out, P, conv_w, conv_s, conv_b,
                     (const float*)xh);
}

// Round 8
// 575.636 us; speedup vs baseline: 1.1828x; 1.1828x over previous
//
#include <hip/hip_runtime.h>

// B=32, C=64, H=W=128, RADIUS=30
// d_ws layout: [0, 134MB) = x_h, [134MB, 268MB) = e   (em never materialized)
// After k_dws completes, x_h is dead; 4KB of it is memset to 0 and used as
// the zero-source for k_edge_final's OOB staging lanes.

__device__ __forceinline__ float2 cmul(float2 a, float2 b) {
  return make_float2(a.x * b.x - a.y * b.y, a.x * b.y + a.y * b.x);
}
__device__ __forceinline__ float2 cadd(float2 a, float2 b) {
  return make_float2(a.x + b.x, a.y + b.y);
}
__device__ __forceinline__ float2 csub(float2 a, float2 b) {
  return make_float2(a.x - b.x, a.y - b.y);
}
__device__ __forceinline__ float2 conjf2(float2 a) {
  return make_float2(a.x, -a.y);
}

// async global->LDS, 16B per lane; LDS dest is wave-uniform base + lane*16.
// CONTRACT: lane 0 of every issuing wave must be active.
__device__ __forceinline__ void gload16(const float* g, void* l) {
  __builtin_amdgcn_global_load_lds(
      (const __attribute__((address_space(1))) void*)g,
      (__attribute__((address_space(3))) void*)l, 16, 0, 0);
}

// LDS layout for FFT: element (r,c) at (r<<7) | ((c ^ (c>>4)) ^ (r&31)).
// Validated round 7: k_fft dropped out of top-5 (was 168us co-leader).
__device__ __forceinline__ int swz(int r, int c) {
  return (r << 7) | ((c ^ (c >> 4)) ^ (r & 31));
}

// ---------------------------------------------------------------------------
// Kernel 1: FFT high-pass, radix-8 passes (unchanged from round 7).
// ---------------------------------------------------------------------------
__device__ __forceinline__ void bf3_fwd(float2 x[8], float2 t0, float2 t1,
                                        float2 t2, float2 t3, float2 tp0,
                                        float2 tp1, float2 tpp) {
  float2 y0 = cadd(x[0], x[4]), y4 = cmul(csub(x[0], x[4]), t0);
  float2 y1 = cadd(x[1], x[5]), y5 = cmul(csub(x[1], x[5]), t1);
  float2 y2 = cadd(x[2], x[6]), y6 = cmul(csub(x[2], x[6]), t2);
  float2 y3 = cadd(x[3], x[7]), y7 = cmul(csub(x[3], x[7]), t3);
  float2 z0 = cadd(y0, y2), z2 = cmul(csub(y0, y2), tp0);
  float2 z1 = cadd(y1, y3), z3 = cmul(csub(y1, y3), tp1);
  float2 z4 = cadd(y4, y6), z6 = cmul(csub(y4, y6), tp0);
  float2 z5 = cadd(y5, y7), z7 = cmul(csub(y5, y7), tp1);
  x[0] = cadd(z0, z1); x[1] = cmul(csub(z0, z1), tpp);
  x[2] = cadd(z2, z3); x[3] = cmul(csub(z2, z3), tpp);
  x[4] = cadd(z4, z5); x[5] = cmul(csub(z4, z5), tpp);
  x[6] = cadd(z6, z7); x[7] = cmul(csub(z6, z7), tpp);
}

__device__ __forceinline__ void bf3_inv(float2 x[8], float2 w0, float2 w10,
                                        float2 w11, float2 w20, float2 w21,
                                        float2 w22, float2 w23) {
  float2 t;
  t = cmul(x[1], w0); float2 y0 = cadd(x[0], t), y1 = csub(x[0], t);
  t = cmul(x[3], w0); float2 y2 = cadd(x[2], t), y3 = csub(x[2], t);
  t = cmul(x[5], w0); float2 y4 = cadd(x[4], t), y5 = csub(x[4], t);
  t = cmul(x[7], w0); float2 y6 = cadd(x[6], t), y7 = csub(x[6], t);
  t = cmul(y2, w10); float2 z0 = cadd(y0, t), z2 = csub(y0, t);
  t = cmul(y3, w11); float2 z1 = cadd(y1, t), z3 = csub(y1, t);
  t = cmul(y6, w10); float2 z4 = cadd(y4, t), z6 = csub(y4, t);
  t = cmul(y7, w11); float2 z5 = cadd(y5, t), z7 = csub(y5, t);
  t = cmul(z4, w20); x[0] = cadd(z0, t); x[4] = csub(z0, t);
  t = cmul(z5, w21); x[1] = cadd(z1, t); x[5] = csub(z1, t);
  t = cmul(z6, w22); x[2] = cadd(z2, t); x[6] = csub(z2, t);
  t = cmul(z7, w23); x[3] = cadd(z3, t); x[7] = csub(z3, t);
}

template <bool COL, int S>
__device__ __forceinline__ void fwd_tri(float2* img, const float2* tw,
                                        int tid) {
  constexpr int m4 = 1 << (S - 2);
#pragma unroll
  for (int k = 0; k < 2; ++k) {
    int g = tid + (k << 10);
    int line = COL ? (g & 127) : (g >> 4);
    int gidx = COL ? (g >> 7) : (g & 15);
    int q = gidx >> (S - 2);
    int j = gidx & (m4 - 1);
    int off0 = (q << (S + 1)) + j;
    int ad[8];
    float2 x[8];
#pragma unroll
    for (int i = 0; i < 8; ++i) {
      int el = off0 + i * m4;
      ad[i] = COL ? swz(el, line) : swz(line, el);
      x[i] = img[ad[i]];
    }
    bf3_fwd(x, tw[j << (6 - S)], tw[(j + m4) << (6 - S)],
            tw[(j + 2 * m4) << (6 - S)], tw[(j + 3 * m4) << (6 - S)],
            tw[j << (7 - S)], tw[(j + m4) << (7 - S)], tw[j << (8 - S)]);
#pragma unroll
    for (int i = 0; i < 8; ++i) img[ad[i]] = x[i];
  }
  __syncthreads();
}

__device__ __forceinline__ void fwd_rows6_g(const float* __restrict__ p0,
                                            const float* __restrict__ p1,
                                            float2* img, const float2* tw,
                                            int tid) {
#pragma unroll
  for (int k = 0; k < 2; ++k) {
    int g = tid + (k << 10);
    int line = g >> 4;
    int j = g & 15;
    float2 x[8];
#pragma unroll
    for (int i = 0; i < 8; ++i) {
      int a = (line << 7) + j + (i << 4);
      x[i] = make_float2(p0[a], p1[a]);
    }
    bf3_fwd(x, tw[j], tw[j + 16], tw[j + 32], tw[j + 48], tw[j << 1],
            tw[(j + 16) << 1], tw[j << 2]);
#pragma unroll
    for (int i = 0; i < 8; ++i) img[swz(line, j + (i << 4))] = x[i];
  }
  __syncthreads();
}

__device__ __forceinline__ void fwd_last_rows(float2* img, int tid) {
#pragma unroll
  for (int k = 0; k < 8; ++k) {
    int g = tid + (k << 10);
    int line = g >> 6;
    int pr = g & 63;
    int e0 = pr << 1;
    int a0 = swz(line, e0), a1 = swz(line, e0 + 1);
    float2 a = img[a0], b = img[a1];
    img[a0] = cadd(a, b);
    img[a1] = csub(a, b);
  }
  __syncthreads();
}

__device__ __forceinline__ void fwd_last_cols_mask(float2* img, int tid) {
#pragma unroll
  for (int k = 0; k < 8; ++k) {
    int g = tid + (k << 10);
    int line = g & 127;
    int pr = g >> 7;
    int e0 = pr << 1;
    int a0 = swz(e0, line), a1 = swz(e0 + 1, line);
    float2 a = img[a0], b = img[a1];
    float2 s = cadd(a, b), d = csub(a, b);
    int v = __brev((unsigned)line) >> 25;
    int dv = v - ((v >= 64) << 7);
    int u0 = __brev((unsigned)e0) >> 25;
    int du0 = u0 - ((u0 >= 64) << 7);
    int u1 = __brev((unsigned)(e0 + 1)) >> 25;
    int du1 = u1 - ((u1 >= 64) << 7);
    int dvv = dv * dv;
    img[a0] = (du0 * du0 + dvv < 900) ? make_float2(0.f, 0.f) : s;
    img[a1] = (du1 * du1 + dvv < 900) ? make_float2(0.f, 0.f) : d;
  }
  __syncthreads();
}

template <bool COL, int S>
__device__ __forceinline__ void inv_tri(float2* img, const float2* tw,
                                        int tid) {
  constexpr int m = 1 << S;
#pragma unroll
  for (int k = 0; k < 2; ++k) {
    int g = tid + (k << 10);
    int line = COL ? (g & 127) : (g >> 4);
    int gidx = COL ? (g >> 7) : (g & 15);
    int q = gidx >> S;
    int j = gidx & (m - 1);
    int off0 = (q << (S + 3)) + j;
    int ad[8];
    float2 x[8];
#pragma unroll
    for (int i = 0; i < 8; ++i) {
      int el = off0 + i * m;
      ad[i] = COL ? swz(el, line) : swz(line, el);
      x[i] = img[ad[i]];
    }
    bf3_inv(x, conjf2(tw[j << (6 - S)]), conjf2(tw[j << (5 - S)]),
            conjf2(tw[(j + m) << (5 - S)]), conjf2(tw[j << (4 - S)]),
            conjf2(tw[(j + m) << (4 - S)]), conjf2(tw[(j + 2 * m) << (4 - S)]),
            conjf2(tw[(j + 3 * m) << (4 - S)]));
#pragma unroll
    for (int i = 0; i < 8; ++i) img[ad[i]] = x[i];
  }
  __syncthreads();
}

__device__ __forceinline__ void inv_last_cols(float2* img, const float2* tw,
                                              int tid) {
#pragma unroll
  for (int k = 0; k < 8; ++k) {
    int g = tid + (k << 10);
    int line = g & 127;
    int j = g >> 7;
    int a0 = swz(j, line), a1 = swz(j + 64, line);
    float2 a = img[a0], b = img[a1];
    float2 t = cmul(b, conjf2(tw[j]));
    img[a0] = cadd(a, t);
    img[a1] = csub(a, t);
  }
  __syncthreads();
}

__device__ __forceinline__ void inv_last_rows_store(const float2* img,
                                                    const float2* tw,
                                                    float* __restrict__ q0,
                                                    float* __restrict__ q1,
                                                    int tid) {
#pragma unroll
  for (int k = 0; k < 8; ++k) {
    int g = tid + (k << 10);
    int line = g >> 6;
    int j = g & 63;
    float2 a = img[swz(line, j)], b = img[swz(line, j + 64)];
    float2 t = cmul(b, conjf2(tw[j]));
    float2 o0 = cadd(a, t), o1 = csub(a, t);
    int p = (line << 7) + j;
    q0[p] = fabsf(o0.x) * 6.103515625e-05f;
    q1[p] = fabsf(o0.y) * 6.103515625e-05f;
    q0[p + 64] = fabsf(o1.x) * 6.103515625e-05f;
    q1[p + 64] = fabsf(o1.y) * 6.103515625e-05f;
  }
}

__global__ __launch_bounds__(1024) void k_fft_hp(const float* __restrict__ x,
                                                 float* __restrict__ xh) {
  __shared__ float2 img[16384];
  __shared__ float2 tw[64];
  const int tid = threadIdx.x;
  const size_t base = (size_t)blockIdx.x * 32768;
  const float* p0 = x + base;
  const float* p1 = p0 + 16384;

  if (tid < 64) {
    float ang = -0.04908738521234052f * (float)tid;
    tw[tid] = make_float2(cosf(ang), sinf(ang));
  }
  __syncthreads();

  fwd_rows6_g(p0, p1, img, tw, tid);
  fwd_tri<false, 3>(img, tw, tid);
  fwd_last_rows(img, tid);
  fwd_tri<true, 6>(img, tw, tid);
  fwd_tri<true, 3>(img, tw, tid);
  fwd_last_cols_mask(img, tid);

  inv_tri<true, 0>(img, tw, tid);
  inv_tri<true, 3>(img, tw, tid);
  inv_last_cols(img, tw, tid);
  inv_tri<false, 0>(img, tw, tid);
  inv_tri<false, 3>(img, tw, tid);
  inv_last_rows_store(img, tw, xh + base, xh + base + 16384, tid);
}

// ---------------------------------------------------------------------------
// Kernel 2: fused DWSConv — REVERTED to the round-6 structure (best measured:
// 167us; round-7's inline-asm counted-vmcnt pipeline regressed to 265us via
// 3x VALU-instruction blowup from schedule pinning). One addition: XCD-aware
// blockIdx swizzle (T1) — L=(bid&7)*256+(bid>>3) gives each XCD a contiguous
// tile range so the 1.56x halo overfetch (FETCH 202MB vs 134 ideal) becomes
// L2 hits instead of HBM re-reads. Bijective: 2048 = 8*256.
// ---------------------------------------------------------------------------
#define DWS_G(chunk, buf)                                                      \
  {                                                                            \
    _Pragma("unroll") for (int k2 = 0; k2 < 4; ++k2) {                         \
      int idx = t + (k2 << 8);                                                 \
      if (idx < 800)                                                           \
        gload16(xh + xbase + (size_t)(chunk) * 131072 + offs[k2],              \
                &inT[buf][idx << 2]);                                          \
    }                                                                          \
  }

#define DWS_FIX(buf)                                                           \
  {                                                                            \
    _Pragma("unroll") for (int k2 = 0; k2 < 4; ++k2) {                         \
      if ((fixm >> k2) & 1)                                                    \
        *(float4*)&inT[buf][(t + (k2 << 8)) << 2] =                            \
            make_float4(0.f, 0.f, 0.f, 0.f);                                   \
    }                                                                          \
  }

__global__ __launch_bounds__(256) void k_dws(
    const float* __restrict__ xh, float* __restrict__ e,
    const float* __restrict__ dw_w, const float* __restrict__ s1,
    const float* __restrict__ b1, const float* __restrict__ pw_w,
    const float* __restrict__ s2, const float* __restrict__ b2) {
  __shared__ __align__(16) float inT[2][3200];  // 2 x (8ch x 10r x 40f)

  const int t = threadIdx.x;
  // XCD-contiguous tile remap: XCD k (= bid%8) owns logical tiles
  // [k*256, (k+1)*256) — contiguous batches/rows -> halo reuse in L2.
  const int L = ((blockIdx.x & 7) << 8) | (blockIdx.x >> 3);
  const int bb = L >> 6;
  const int ty = (L >> 2) & 15;
  const int tx = L & 3;
  const int r = t >> 5;
  const int x = t & 31;

  const int gy0 = (ty << 3) - 1;   // first halo row
  const int gxb = (tx << 5) - 4;   // float col of granule 0
  const size_t xbase = (size_t)bb << 20;
  const bool bfix = (ty == 0) | (ty == 15) | (tx == 0) | (tx == 3);

  // per-thread staging offsets + OOB fix mask (chunk-invariant)
  unsigned fixm = 0;
  int offs[4];
#pragma unroll
  for (int k2 = 0; k2 < 4; ++k2) {
    int idx = t + (k2 << 8);
    offs[k2] = 0;
    if (idx < 800) {
      int c = idx / 100;          // 0..7
      int rem = idx - c * 100;
      int row = rem / 10;
      int g = rem - row * 10;
      int grow = gy0 + row;
      int gcol = gxb + (g << 2);
      if ((grow < 0) | (grow > 127) | (gcol < 0) | (gcol > 124))
        fixm |= (1u << k2);
      int grc = grow < 0 ? 0 : (grow > 127 ? 127 : grow);
      int gcc = gcol < 0 ? 0 : (gcol > 124 ? 124 : gcol);
      offs[k2] = (c << 14) + (grc << 7) + gcc;
    }
  }

  float acc[64];
#pragma unroll
  for (int o = 0; o < 64; ++o) acc[o] = 0.f;

  DWS_G(0, 0);
  __syncthreads();  // drains vmcnt -> buf0 raw data ready

#pragma unroll 1
  for (int chunk = 0; chunk < 8; ++chunk) {
    if (bfix) {           // block-uniform branch; vmcnt already 0 here
      DWS_FIX(chunk & 1);
      __syncthreads();    // fix visible before compute
    }
    if (chunk < 7) DWS_G(chunk + 1, (chunk + 1) & 1);  // async, in flight
    const float* base = &inT[chunk & 1][0];

    float dwv[8];
#pragma unroll
    for (int c = 0; c < 8; ++c) {
      const int cg = (chunk << 3) + c;
      const float* wp = dw_w + cg * 9;          // uniform -> s_load
      const float* p = base + c * 400 + r * 40 + x + 3;  // center col = x+4
      float s = wp[0] * p[0];
      s = fmaf(wp[1], p[1], s);
      s = fmaf(wp[2], p[2], s);
      s = fmaf(wp[3], p[40], s);
      s = fmaf(wp[4], p[41], s);
      s = fmaf(wp[5], p[42], s);
      s = fmaf(wp[6], p[80], s);
      s = fmaf(wp[7], p[81], s);
      s = fmaf(wp[8], p[82], s);
      dwv[c] = fmaxf(fmaf(s, s1[cg], b1[cg]), 0.f);
    }

#pragma unroll
    for (int o = 0; o < 64; ++o) {
      const float* w = pw_w + (o << 6) + (chunk << 3);
#pragma unroll
      for (int c = 0; c < 8; ++c) acc[o] = fmaf(w[c], dwv[c], acc[o]);
    }
    __syncthreads();  // drains chunk+1 loads; protects buffer reuse
  }

  const int gy = (ty << 3) + r;
  const int gx = (tx << 5) + x;
#pragma unroll
  for (int o = 0; o < 64; ++o) {
    float ev = fmaxf(fmaf(acc[o], s2[o], b2[o]), 0.f);
    e[(((size_t)bb * 64 + o) << 14) + (gy << 7) + gx] = ev;
  }
}

// ---------------------------------------------------------------------------
// Kernel 3: branches + edge + final (round-6 structure) + XCD-aware remap:
// L=(bid&7)*32+(bid>>3) (bijective: 256 = 8*32) — ty-adjacent tiles (sharing
// 10 e-halo rows) stay on one XCD's L2.
// ---------------------------------------------------------------------------
struct BrParams {
  const float *dw1w, *dw1s, *dw1b, *pw1w, *pw1s, *pw1b;
  const float *dw2w, *dw2s, *dw2b, *pw2w, *pw2s, *pw2b;
  const float *dw3w, *dw3s, *dw3b, *pw3w, *pw3s, *pw3b;
  const float *dw4w, *dw4s, *dw4b, *pw4w, *pw4s, *pw4b;
};

#define EDGE_G(chunk, buf)                                                     \
  {                                                                            \
    _Pragma("unroll") for (int k2 = 0; k2 < 9; ++k2) {                         \
      int idx = t + (k2 << 8);                                                 \
      if (idx < 2080) {                                                        \
        const float* src = eg + ebase + (size_t)(chunk) * 32768 + eoffs[k2];   \
        if ((fixm >> k2) & 1) src = zp;  /* per-lane cndmask */                \
        gload16(src, &sE[buf][idx << 2]);                                      \
      }                                                                        \
    }                                                                          \
  }

__global__ __launch_bounds__(256) void k_edge_final(
    const float* __restrict__ eg, const float* __restrict__ xg,
    float* __restrict__ out, BrParams P, const float* __restrict__ cw,
    const float* __restrict__ cs, const float* __restrict__ cb,
    const float* __restrict__ zp) {
  __shared__ __align__(16) float sE[2][8320];  // 2 x (2ch x 26r x 160f)
  __shared__ float w2r[768], w3r[768], w4r[768];  // [c][12] repacked
  __shared__ float chp[1024];          // [c][16] packed params
  __shared__ float dwSs[4][64], dwBs[4][64], gs[4][64];
  __shared__ float dw1Ws[64], cws[64];
  __shared__ float pss[4][16], pbs[4][16];
  __shared__ float KbS, swS;

  const int t = threadIdx.x;
  const int L = ((blockIdx.x & 7) << 5) | (blockIdx.x >> 3);
  const int bb = L >> 3;               // batch
  const int ty = L & 7;                // row-tile of 16
  const int r = t >> 4;                // 0..15
  const int x0 = (t & 15) << 3;        // 0..120, step 8
  const int gy = (ty << 4) + r;
  const int gy0 = (ty << 4) - 5;
  const size_t ebase = (size_t)bb << 20;

  for (int i = t; i < 576; i += 256) {
    int row = i / 9, q = i - row * 9;
    w2r[row * 12 + q] = P.dw2w[i];
    w3r[row * 12 + q] = P.dw3w[i];
    w4r[row * 12 + q] = P.dw4w[i];
  }
  if (t < 64) {
    dw1Ws[t] = P.dw1w[t];
    cws[t] = cw[t];
    dwSs[0][t] = P.dw1s[t]; dwBs[0][t] = P.dw1b[t];
    dwSs[1][t] = P.dw2s[t]; dwBs[1][t] = P.dw2b[t];
    dwSs[2][t] = P.dw3s[t]; dwBs[2][t] = P.dw3b[t];
    dwSs[3][t] = P.dw4s[t]; dwBs[3][t] = P.dw4b[t];
  }
  if (t < 16) {
    pss[0][t] = P.pw1s[t]; pbs[0][t] = P.pw1b[t];
    pss[1][t] = P.pw2s[t]; pbs[1][t] = P.pw2b[t];
    pss[2][t] = P.pw3s[t]; pbs[2][t] = P.pw3b[t];
    pss[3][t] = P.pw4s[t]; pbs[3][t] = P.pw4b[t];
  }
  __syncthreads();
  {
    const int q = t >> 6, c = t & 63;
    const float* pwW = (q == 0) ? P.pw1w : (q == 1) ? P.pw2w
                        : (q == 2) ? P.pw3w : P.pw4w;
    float gv = 0.f;
#pragma unroll
    for (int o = 0; o < 16; ++o)
      gv = fmaf(cws[(q << 4) + o] * pss[q][o], pwW[(o << 6) + c], gv);
    gs[q][c] = gv;
  }
  if (t == 0) {
    float kb = 0.f, sw = 0.f;
#pragma unroll
    for (int i = 0; i < 64; ++i) {
      kb = fmaf(cws[i], pbs[i >> 4][i & 15], kb);
      sw += cws[i];
    }
    KbS = kb;
    swS = sw;
  }
  __syncthreads();
  if (t < 64) {
    float* cp = &chp[t << 4];
    cp[0] = dw1Ws[t];  cp[1] = cws[t];
    cp[2] = dwSs[0][t]; cp[3] = dwBs[0][t];
    cp[4] = dwSs[1][t]; cp[5] = dwBs[1][t];
    cp[6] = dwSs[2][t]; cp[7] = dwBs[2][t];
    cp[8] = dwSs[3][t]; cp[9] = dwBs[3][t];
    cp[10] = gs[0][t]; cp[11] = gs[1][t];
    cp[12] = gs[2][t]; cp[13] = gs[3][t];
  }

  unsigned fixm = 0;
  int eoffs[9];
#pragma unroll
  for (int k2 = 0; k2 < 9; ++k2) {
    int idx = t + (k2 << 8);
    eoffs[k2] = 0;
    if (idx < 2080) {
      int jj = idx >= 1040;
      int rem = idx - (jj ? 1040 : 0);
      int row = rem / 40;
      int q = rem - row * 40;
      int s = q ^ (q >> 3);
      int grow = gy0 + row;
      if ((grow < 0) | (grow > 127) | (s < 2) | (s > 33)) fixm |= (1u << k2);
      int grc = grow < 0 ? 0 : (grow > 127 ? 127 : grow);
      int sc = s < 2 ? 2 : (s > 33 ? 33 : s);
      eoffs[k2] = (jj << 14) + (grc << 7) + (sc << 2) - 8;
    }
  }

  const int gbase = (t & 15) << 1;
  int so[6];
#pragma unroll
  for (int k = 0; k < 6; ++k) {
    int g = gbase + k;
    so[k] = (g ^ (g >> 3)) << 2;
  }

  EDGE_G(0, 0);
  __syncthreads();  // drains vmcnt + chp writes

  float eacc[8], es8[8], sxa[8];
#pragma unroll
  for (int k = 0; k < 8; ++k) { eacc[k] = 0.f; es8[k] = 0.f; sxa[k] = 0.f; }

  const float csv = cs[0], cbv = cb[0];

#pragma unroll 1
  for (int c = 0; c < 32; ++c) {
    if (c + 1 < 32) EDGE_G(c + 1, (c + 1) & 1);  // async, in flight
    const float* bp = &sE[c & 1][0];
#pragma unroll 1
    for (int j = 0; j < 2; ++j) {
      const int cg = (c << 1) + j;
      const float* ldc = bp + j * 4160;
      const float* xp = xg + (((size_t)bb * 64 + cg) << 14) + (gy << 7) + x0;
      float xv[8];
      *(float4*)&xv[0] = *(const float4*)xp;
      *(float4*)&xv[4] = *(const float4*)(xp + 4);
      const float4 Q0 = *(const float4*)&chp[cg << 4];
      const float4 Q1 = *(const float4*)&chp[(cg << 4) + 4];
      const float4 Q2 = *(const float4*)&chp[(cg << 4) + 8];
      const float4 Q3 = *(const float4*)&chp[(cg << 4) + 12];

      float cr[24];
      const float* rowc = ldc + (r + 5) * 160;
      *(float4*)&cr[0] = *(const float4*)(rowc + so[0]);
      *(float4*)&cr[4] = *(const float4*)(rowc + so[1]);
      *(float4*)&cr[8] = *(const float4*)(rowc + so[2]);
      *(float4*)&cr[12] = *(const float4*)(rowc + so[3]);
      *(float4*)&cr[16] = *(const float4*)(rowc + so[4]);
      *(float4*)&cr[20] = *(const float4*)(rowc + so[5]);

#pragma unroll
      for (int k = 0; k < 8; ++k) {
        float ec = cr[8 + k];
        es8[k] = fmaf(Q0.y, ec, es8[k]);
        float d0 = fmaxf(fmaf(ec * Q0.x, Q0.z, Q0.w), 0.f);
        eacc[k] = fmaf(Q2.z, d0, eacc[k]);
      }
      float mm[24], pp[24];
      {
        const float4 w2a = *(const float4*)&w2r[cg * 12];
        const float4 w2b = *(const float4*)&w2r[cg * 12 + 4];
        const float4 w2c = *(const float4*)&w2r[cg * 12 + 8];
        const float* rm = ldc + (r + 4) * 160;
        const float* rp = ldc + (r + 6) * 160;
        *(float4*)&mm[0] = *(const float4*)(rm + so[1]);
        *(float4*)&mm[4] = *(const float4*)(rm + so[2]);
        *(float4*)&mm[8] = *(const float4*)(rm + so[3]);
        *(float4*)&mm[12] = *(const float4*)(rm + so[4]);
        *(float4*)&pp[0] = *(const float4*)(rp + so[1]);
        *(float4*)&pp[4] = *(const float4*)(rp + so[2]);
        *(float4*)&pp[8] = *(const float4*)(rp + so[3]);
        *(float4*)&pp[12] = *(const float4*)(rp + so[4]);
#pragma unroll
        for (int k = 0; k < 8; ++k) {
          float s = w2a.x * mm[3 + k];
          s = fmaf(w2a.y, mm[4 + k], s);
          s = fmaf(w2a.z, mm[5 + k], s);
          s = fmaf(w2a.w, cr[7 + k], s);
          s = fmaf(w2b.x, cr[8 + k], s);
          s = fmaf(w2b.y, cr[9 + k], s);
          s = fmaf(w2b.z, pp[3 + k], s);
          s = fmaf(w2b.w, pp[4 + k], s);
          s = fmaf(w2c.x, pp[5 + k], s);
          float d1 = fmaxf(fmaf(s, Q1.x, Q1.y), 0.f);
          eacc[k] = fmaf(Q2.w, d1, eacc[k]);
        }
      }
      {
        const float4 w3a = *(const float4*)&w3r[cg * 12];
        const float4 w3b = *(const float4*)&w3r[cg * 12 + 4];
        const float4 w3c = *(const float4*)&w3r[cg * 12 + 8];
        const float* rm = ldc + (r + 2) * 160;
        const float* rp = ldc + (r + 8) * 160;
        *(float4*)&mm[0] = *(const float4*)(rm + so[1]);
        *(float4*)&mm[4] = *(const float4*)(rm + so[2]);
        *(float4*)&mm[8] = *(const float4*)(rm + so[3]);
        *(float4*)&mm[12] = *(const float4*)(rm + so[4]);
        *(float4*)&pp[0] = *(const float4*)(rp + so[1]);
        *(float4*)&pp[4] = *(const float4*)(rp + so[2]);
        *(float4*)&pp[8] = *(const float4*)(rp + so[3]);
        *(float4*)&pp[12] = *(const float4*)(rp + so[4]);
#pragma unroll
        for (int k = 0; k < 8; ++k) {
          float s = w3a.x * mm[1 + k];
          s = fmaf(w3a.y, mm[4 + k], s);
          s = fmaf(w3a.z, mm[7 + k], s);
          s = fmaf(w3a.w, cr[5 + k], s);
          s = fmaf(w3b.x, cr[8 + k], s);
          s = fmaf(w3b.y, cr[11 + k], s);
          s = fmaf(w3b.z, pp[1 + k], s);
          s = fmaf(w3b.w, pp[4 + k], s);
          s = fmaf(w3c.x, pp[7 + k], s);
          float d2 = fmaxf(fmaf(s, Q1.z, Q1.w), 0.f);
          eacc[k] = fmaf(Q3.x, d2, eacc[k]);
        }
      }
      {
        const float4 w4a = *(const float4*)&w4r[cg * 12];
        const float4 w4b = *(const float4*)&w4r[cg * 12 + 4];
        const float4 w4c = *(const float4*)&w4r[cg * 12 + 8];
        const float* rm = ldc + (r + 0) * 160;
        const float* rp = ldc + (r + 10) * 160;
        *(float4*)&mm[0] = *(const float4*)(rm + so[0]);
        *(float4*)&mm[4] = *(const float4*)(rm + so[1]);
        *(float4*)&mm[8] = *(const float4*)(rm + so[2]);
        *(float4*)&mm[12] = *(const float4*)(rm + so[3]);
        *(float4*)&mm[16] = *(const float4*)(rm + so[4]);
        *(float4*)&mm[20] = *(const float4*)(rm + so[5]);
        *(float4*)&pp[0] = *(const float4*)(rp + so[0]);
        *(float4*)&pp[4] = *(const float4*)(rp + so[1]);
        *(float4*)&pp[8] = *(const float4*)(rp + so[2]);
        *(float4*)&pp[12] = *(const float4*)(rp + so[3]);
        *(float4*)&pp[16] = *(const float4*)(rp + so[4]);
        *(float4*)&pp[20] = *(const float4*)(rp + so[5]);
#pragma unroll
        for (int k = 0; k < 8; ++k) {
          float s = w4a.x * mm[3 + k];
          s = fmaf(w4a.y, mm[8 + k], s);
          s = fmaf(w4a.z, mm[13 + k], s);
          s = fmaf(w4a.w, cr[3 + k], s);
          s = fmaf(w4b.x, cr[8 + k], s);
          s = fmaf(w4b.y, cr[13 + k], s);
          s = fmaf(w4b.z, pp[3 + k], s);
          s = fmaf(w4b.w, pp[8 + k], s);
          s = fmaf(w4c.x, pp[13 + k], s);
          float d3 = fmaxf(fmaf(s, Q2.x, Q2.y), 0.f);
          eacc[k] = fmaf(Q3.y, d3, eacc[k]);
        }
      }
#pragma unroll
      for (int k = 0; k < 8; ++k) sxa[k] = fmaf(Q0.y, xv[k], sxa[k]);
    }
    __syncthreads();  // drains c+1 loads; protects buffer reuse
  }

  const float kb = KbS, sw = swS;
  float ov[8];
#pragma unroll
  for (int k = 0; k < 8; ++k) {
    float ee = fmaxf(fmaf(eacc[k] + kb + es8[k], csv, cbv), 0.f);
    ov[k] = fmaf(sxa[k] + ee * sw, csv, cbv);
  }
  float* op = out + ((size_t)bb << 14) + (gy << 7) + x0;
  *(float4*)op = *(float4*)&ov[0];
  *(float4*)(op + 4) = *(float4*)&ov[4];
}

// ---------------------------------------------------------------------------
extern "C" void kernel_launch(void* const* d_in, const int* in_sizes, int n_in,
                              void* d_out, int out_size, void* d_ws,
                              size_t ws_size, hipStream_t stream) {
  (void)in_sizes; (void)n_in; (void)out_size; (void)ws_size;
  const float* x = (const float*)d_in[0];
  const float* dws_dw = (const float*)d_in[1];
  const float* dws_s1 = (const float*)d_in[2];
  const float* dws_b1 = (const float*)d_in[3];
  const float* dws_pw = (const float*)d_in[4];
  const float* dws_s2 = (const float*)d_in[5];
  const float* dws_b2 = (const float*)d_in[6];
  BrParams P;
  P.dw1w = (const float*)d_in[7];  P.dw1s = (const float*)d_in[8];
  P.dw1b = (const float*)d_in[9];  P.pw1w = (const float*)d_in[10];
  P.pw1s = (const float*)d_in[11]; P.pw1b = (const float*)d_in[12];
  P.dw2w = (const float*)d_in[13]; P.dw2s = (const float*)d_in[14];
  P.dw2b = (const float*)d_in[15]; P.pw2w = (const float*)d_in[16];
  P.pw2s = (const float*)d_in[17]; P.pw2b = (const float*)d_in[18];
  P.dw3w = (const float*)d_in[19]; P.dw3s = (const float*)d_in[20];
  P.dw3b = (const float*)d_in[21]; P.pw3w = (const float*)d_in[22];
  P.pw3s = (const float*)d_in[23]; P.pw3b = (const float*)d_in[24];
  P.dw4w = (const float*)d_in[25]; P.dw4s = (const float*)d_in[26];
  P.dw4b = (const float*)d_in[27]; P.pw4w = (const float*)d_in[28];
  P.pw4s = (const float*)d_in[29]; P.pw4b = (const float*)d_in[30];
  const float* conv_w = (const float*)d_in[31];
  const float* conv_s = (const float*)d_in[32];
  const float* conv_b = (const float*)d_in[33];

  float* xh = (float*)d_ws;                 // 134 MB
  float* e = xh + (size_t)33554432;         // 134 MB

  hipLaunchKernelGGL(k_fft_hp, dim3(1024), dim3(1024), 0, stream, x, xh);
  hipLaunchKernelGGL(k_dws, dim3(2048), dim3(256), 0, stream, xh, e, dws_dw,
                     dws_s1, dws_b1, dws_pw, dws_s2, dws_b2);
  // x_h is dead from here; zero 4KB of it as the OOB source for k_edge_final
  hipMemsetAsync(xh, 0, 4096, stream);
  hipLaunchKernelGGL(k_edge_final, dim3(256), dim3(256), 0, stream, e, x,
                     (float*)d_out, P, conv_w, conv_s, conv_b,
                     (const float*)xh);
}